// Round 8
// baseline (684.006 us; speedup 1.0000x reference)
//
#include <hip/hip_runtime.h>

// Problem constants (match reference)
#define CB   64
#define CS   512
#define CD   128
#define CH   4
#define CFF  512
#define CL   4
#define NEG_BIG -3.0e38f
#define SCALE 0.17677669529663687f   // 1/sqrt(32)
#define EXSC  0.25505654050961364f   // SCALE * log2(e)

typedef __attribute__((ext_vector_type(8))) short short8;
typedef __attribute__((ext_vector_type(4))) float f32x4;
typedef __attribute__((ext_vector_type(4))) unsigned int u32x4;

static __device__ __forceinline__ unsigned short f2b(float f) {
  union { float f; unsigned int u; } v; v.f = f;
  unsigned int u = v.u;
  unsigned int r = (u + 0x7fffu + ((u >> 16) & 1u)) >> 16;  // RNE
  return (unsigned short)r;
}

// ---------------------------------------------------------------------------
// All weights fp32 -> bf16 in one launch (block ranges: 192 | 64 | 256 | 256).
// W2 is stored PERMUTED: within each 32-col chunk, col n goes to position
// pos = 8*((n&15)>>2) + 4*((n>>4)&1) + (n&3)  -- the same permutation as vtb,
// so FFN2's B-fragment (k-map 4lg+(e&3)+16(e>>2)) is one contiguous 16B load.
// ---------------------------------------------------------------------------
__global__ void k_cvt_all(const float* __restrict__ inw, const float* __restrict__ outw,
                          const float* __restrict__ ffw1, const float* __restrict__ ffw2,
                          unsigned short* __restrict__ wq, unsigned short* __restrict__ wo,
                          unsigned short* __restrict__ w1, unsigned short* __restrict__ w2) {
  int bid = blockIdx.x;
  if (bid < 512) {
    const float* src; unsigned short* dst; int base;
    if (bid < 192)      { src = inw;  dst = wq; base = bid; }
    else if (bid < 256) { src = outw; dst = wo; base = bid - 192; }
    else                { src = ffw1; dst = w1; base = bid - 256; }
    int i = base * 256 + threadIdx.x;
    float4 v = ((const float4*)src)[i];
    ((ushort4*)dst)[i] = make_ushort4(f2b(v.x), f2b(v.y), f2b(v.z), f2b(v.w));
  } else {
    int i = (bid - 512) * 256 + threadIdx.x;    // float4 group
    int flat = i * 4;
    int row = flat >> 9;                        // layer*128 + dout
    int n = flat & 511;                         // col, multiple of 4
    float4 v = ((const float4*)ffw2)[i];
    int pos = (n & 480) + 8 * ((n & 15) >> 2) + 4 * ((n >> 4) & 1);
    *(ushort4*)&w2[(size_t)row * 512 + pos] =
        make_ushort4(f2b(v.x), f2b(v.y), f2b(v.z), f2b(v.w));
  }
}

// ---------------------------------------------------------------------------
// Embedding + feature overrides; fp32 + bf16 copies of feat.
// ---------------------------------------------------------------------------
__global__ void k_embed(const int* __restrict__ tok, const int* __restrict__ picked,
                        const int* __restrict__ skipped, const int* __restrict__ nupg,
                        const float* __restrict__ emb, float* __restrict__ featf,
                        unsigned short* __restrict__ featb) {
  int idx = blockIdx.x * 256 + threadIdx.x;   // over B*S*32 float4
  int tp = idx >> 5, c4 = idx & 31;
  int t = tok[tp];
  float4 v = ((const float4*)emb)[t * 32 + c4];
  if (c4 == 0) {
    int b = tp >> 9, s = tp & 511;
    int nc = picked[b] + skipped[b];
    v.x = (s >= nc) ? 1.f : 0.f;
    v.y = (nupg[tp] > 0) ? 1.f : 0.f;
  }
  ((float4*)featf)[idx] = v;
  ((ushort4*)featb)[idx] = make_ushort4(f2b(v.x), f2b(v.y), f2b(v.z), f2b(v.w));
}

// ---------------------------------------------------------------------------
// QKV GEMM, register-direct, head-major outputs (unchanged from round 7).
// ---------------------------------------------------------------------------
__global__ __launch_bounds__(256, 2) void k_gemm_qkv(
    const unsigned short* __restrict__ A, const unsigned short* __restrict__ W,
    const float* __restrict__ bias, unsigned short* __restrict__ qb,
    unsigned short* __restrict__ kb, unsigned short* __restrict__ vtb) {
  const int tid = threadIdx.x;
  const int m0 = blockIdx.x * 128;
  const int y = blockIdx.y;           // 0=Q, 1=K, 2=V
  const int n0 = y * 128;
  const int lane = tid & 63, wid = tid >> 6;
  const int wm = wid >> 1, wn = wid & 1;
  const int lg = lane >> 4, r = lane & 15;

  f32x4 acc[4][4];
#pragma unroll
  for (int mi = 0; mi < 4; ++mi)
#pragma unroll
    for (int ni = 0; ni < 4; ++ni) acc[mi][ni] = (f32x4){0.f, 0.f, 0.f, 0.f};

  const unsigned short* Ab = A + (size_t)(m0 + wm * 64 + r) * 128 + lg * 8;
  const unsigned short* Wb = W + (size_t)(n0 + wn * 64 + r) * 128 + lg * 8;
#pragma unroll
  for (int kc = 0; kc < 4; ++kc) {
    short8 af[4], wf[4];
#pragma unroll
    for (int mi = 0; mi < 4; ++mi) af[mi] = *(const short8*)(Ab + mi * 2048 + kc * 32);
#pragma unroll
    for (int ni = 0; ni < 4; ++ni) wf[ni] = *(const short8*)(Wb + ni * 2048 + kc * 32);
#pragma unroll
    for (int mi = 0; mi < 4; ++mi)
#pragma unroll
      for (int ni = 0; ni < 4; ++ni)
        acc[mi][ni] = __builtin_amdgcn_mfma_f32_16x16x32_bf16(
            af[mi], wf[ni], acc[mi][ni], 0, 0, 0);
  }

  const int bidx = m0 >> 9;  // batch (128-row tiles never straddle b)
  if (y < 2) {
    unsigned short* dst = y ? kb : qb;
    const float sc = y ? 1.f : EXSC;
#pragma unroll
    for (int mi = 0; mi < 4; ++mi)
#pragma unroll
      for (int ni = 0; ni < 4; ++ni) {
        int cl = wn * 64 + ni * 16 + r;           // col within 128-section
        int h = cl >> 5, dd = cl & 31;
        float bia = bias[n0 + cl];
        unsigned short* dp =
            dst + ((size_t)(bidx * 4 + h) * 512) * 32 + dd;
#pragma unroll
        for (int reg = 0; reg < 4; ++reg) {
          int s = (m0 + wm * 64 + mi * 16 + 4 * lg + reg) & 511;
          dp[(size_t)s * 32] = f2b((acc[mi][ni][reg] + bia) * sc);
        }
      }
  } else {
#pragma unroll
    for (int mi = 0; mi < 4; ++mi)
#pragma unroll
      for (int ni = 0; ni < 4; ++ni) {
        int cl = wn * 64 + ni * 16 + r;
        int h = cl >> 5, dd = cl & 31;
        float bia = bias[256 + cl];
        int s4 = (m0 + wm * 64 + mi * 16 + 4 * lg) & 511;  // multiple of 4
        int chunk = s4 >> 5, jl = s4 & 31;
        int p = 8 * ((jl & 15) >> 2) + 4 * (jl >> 4);      // jl&3 == 0
        ushort4 pk = make_ushort4(
            f2b(acc[mi][ni][0] + bia), f2b(acc[mi][ni][1] + bia),
            f2b(acc[mi][ni][2] + bia), f2b(acc[mi][ni][3] + bia));
        *(ushort4*)&vtb[((size_t)(bidx * 4 + h) * 32 + dd) * 512 + chunk * 32 + p] = pk;
      }
  }
}

// ---------------------------------------------------------------------------
// Flash attention v2 (unchanged from round 7, passing).
// ---------------------------------------------------------------------------
__global__ __launch_bounds__(512, 1) void k_attn2(
    const unsigned short* __restrict__ qb, const unsigned short* __restrict__ kb,
    const unsigned short* __restrict__ vtb, const int* __restrict__ npadp,
    const int* __restrict__ picked, const int* __restrict__ skipped,
    unsigned short* __restrict__ obufb) {
  __shared__ __align__(16) unsigned short Ks[CS * 40];   // 40KB
  __shared__ __align__(16) unsigned short Vt[32 * CS];   // 32KB
  const int bh = blockIdx.x, b = bh >> 2, h = bh & 3;
  const int tid = threadIdx.x;
  const unsigned short* qbp = qb + ((size_t)bh * 512) * 32;
  const unsigned short* kbp = kb + ((size_t)bh * 512) * 32;
  const unsigned short* vtp = vtb + ((size_t)bh * 32) * 512;
#pragma unroll
  for (int i = 0; i < 4; ++i) {
    int f = tid + i * 512;                       // [0, 2048)
    int row = f >> 2, c = f & 3;
    *(uint4*)&Ks[row * 40 + c * 8] = *(const uint4*)(kbp + row * 32 + c * 8);
    int rowd = f >> 6, c16 = f & 63;
    *(uint4*)((char*)Vt + rowd * 1024 + ((c16 * 16) ^ ((rowd & 7) << 4))) =
        *(const uint4*)(vtp + rowd * 512 + c16 * 8);
  }
  const int lane = tid & 63, w = tid >> 6;
  const int lg = lane >> 4, r = lane & 15;
  const int npd = npadp[b];
  const int jhi_mid = CS - (picked[b] + skipped[b]);
  short8 onesf;
#pragma unroll
  for (int e = 0; e < 8; ++e) onesf[e] = (short)0x3F80;  // bf16 1.0
  __syncthreads();

  short8 qf[4];
  int jhiR[4];
#pragma unroll
  for (int qt = 0; qt < 4; ++qt) {
    int q = w * 64 + qt * 16 + r;
    qf[qt] = *(const short8*)(qbp + (size_t)q * 32 + 8 * lg);
    jhiR[qt] = (q < jhi_mid) ? jhi_mid : CS;
  }
  f32x4 aO0[4], aO1[4], aL[4];
#pragma unroll
  for (int qt = 0; qt < 4; ++qt) {
    aO0[qt] = (f32x4){0.f, 0.f, 0.f, 0.f};
    aO1[qt] = (f32x4){0.f, 0.f, 0.f, 0.f};
    aL[qt]  = (f32x4){0.f, 0.f, 0.f, 0.f};
  }

  for (int jc = 0; jc < 16; ++jc) {
    const int j0 = jc * 32;
    short8 kf0 = *(const short8*)&Ks[(j0 + r) * 40 + 8 * lg];
    short8 kf1 = *(const short8*)&Ks[(j0 + 16 + r) * 40 + 8 * lg];
    const int jby = (j0 * 2 + 16 * lg) ^ ((r & 7) << 4);
    short8 vf0 = *(const short8*)((const char*)Vt + r * 1024 + jby);
    short8 vf1 = *(const short8*)((const char*)Vt + (16 + r) * 1024 + jby);
#pragma unroll
    for (int qt = 0; qt < 4; ++qt) {
      f32x4 z = (f32x4){0.f, 0.f, 0.f, 0.f};
      f32x4 s0 = __builtin_amdgcn_mfma_f32_16x16x32_bf16(kf0, qf[qt], z, 0, 0, 0);
      f32x4 s1 = __builtin_amdgcn_mfma_f32_16x16x32_bf16(kf1, qf[qt], z, 0, 0, 0);
      float p0[4], p1[4];
#pragma unroll
      for (int g = 0; g < 4; ++g) {
        p0[g] = exp2f(fminf(s0[g], 43.f));
        p1[g] = exp2f(fminf(s1[g], 43.f));
      }
      if (jc == 0) {
#pragma unroll
        for (int g = 0; g < 4; ++g)
          p0[g] = (4 * lg + g >= npd) ? p0[g] : 0.f;
      }
      if (jc == 15) {
#pragma unroll
        for (int g = 0; g < 4; ++g)
          p1[g] = (496 + 4 * lg + g < jhiR[qt]) ? p1[g] : 0.f;
      }
      unsigned int d0 = ((unsigned int)f2b(p0[1]) << 16) | f2b(p0[0]);
      unsigned int d1 = ((unsigned int)f2b(p0[3]) << 16) | f2b(p0[2]);
      unsigned int d2 = ((unsigned int)f2b(p1[1]) << 16) | f2b(p1[0]);
      unsigned int d3 = ((unsigned int)f2b(p1[3]) << 16) | f2b(p1[2]);
      u32x4 pd = (u32x4){d0, d1, d2, d3};
      short8 pa = __builtin_bit_cast(short8, pd);
      aL[qt]  = __builtin_amdgcn_mfma_f32_16x16x32_bf16(pa, onesf, aL[qt], 0, 0, 0);
      aO0[qt] = __builtin_amdgcn_mfma_f32_16x16x32_bf16(pa, vf0, aO0[qt], 0, 0, 0);
      aO1[qt] = __builtin_amdgcn_mfma_f32_16x16x32_bf16(pa, vf1, aO1[qt], 0, 0, 0);
    }
  }

#pragma unroll
  for (int qt = 0; qt < 4; ++qt)
#pragma unroll
    for (int g = 0; g < 4; ++g) {
      int qg = w * 64 + qt * 16 + 4 * lg + g;
      float inv = 1.f / aL[qt][g];
      unsigned short o0 = f2b(aO0[qt][g] * inv);
      unsigned short o1 = f2b(aO1[qt][g] * inv);
      if (qg < npd) {  // pad row: softmax over {qg} -> output = V[qg] exactly
        int p = 8 * (qg >> 2) + (qg & 3);  // qg < 16 -> chunk 0
        o0 = *(const unsigned short*)((const char*)Vt + r * 1024 +
                                      ((2 * p) ^ ((r & 7) << 4)));
        o1 = *(const unsigned short*)((const char*)Vt + (16 + r) * 1024 +
                                      ((2 * p) ^ ((r & 7) << 4)));
      }
      unsigned short* op = obufb + ((size_t)(b * 512 + qg)) * 128 + h * 32;
      op[r] = o0;
      op[16 + r] = o1;
    }
}

// ---------------------------------------------------------------------------
// Register-direct MFMA GEMM (K=128) with +bias +residual -> LN epilogue.
// (outproj; unchanged from round 7)
// ---------------------------------------------------------------------------
__global__ __launch_bounds__(256, 2) void k_gemm_ln(
    const unsigned short* __restrict__ A, const unsigned short* __restrict__ W,
    const float* __restrict__ bias, float* __restrict__ outf,
    unsigned short* __restrict__ outb, const float* __restrict__ resf,
    const float* __restrict__ gam, const float* __restrict__ bet) {
  const int tid = threadIdx.x;
  const int m0 = blockIdx.x * 128;
  const int lane = tid & 63, wid = tid >> 6;
  const int wm = wid >> 1, wn = wid & 1;
  const int lg = lane >> 4, r = lane & 15;

  f32x4 acc[4][4];
#pragma unroll
  for (int mi = 0; mi < 4; ++mi)
#pragma unroll
    for (int ni = 0; ni < 4; ++ni) acc[mi][ni] = (f32x4){0.f, 0.f, 0.f, 0.f};

  const unsigned short* Ab = A + (size_t)(m0 + wm * 64 + r) * 128 + lg * 8;
  const unsigned short* Wb = W + (size_t)(wn * 64 + r) * 128 + lg * 8;
#pragma unroll
  for (int kc = 0; kc < 4; ++kc) {
    short8 af[4], wf[4];
#pragma unroll
    for (int mi = 0; mi < 4; ++mi) af[mi] = *(const short8*)(Ab + mi * 2048 + kc * 32);
#pragma unroll
    for (int ni = 0; ni < 4; ++ni) wf[ni] = *(const short8*)(Wb + ni * 2048 + kc * 32);
#pragma unroll
    for (int mi = 0; mi < 4; ++mi)
#pragma unroll
      for (int ni = 0; ni < 4; ++ni)
        acc[mi][ni] = __builtin_amdgcn_mfma_f32_16x16x32_bf16(
            af[mi], wf[ni], acc[mi][ni], 0, 0, 0);
  }

  __shared__ __align__(16) float Y[128 * 132];
#pragma unroll
  for (int mi = 0; mi < 4; ++mi)
#pragma unroll
    for (int ni = 0; ni < 4; ++ni) {
      int col = wn * 64 + ni * 16 + r;
      float bia = bias[col];
#pragma unroll
      for (int reg = 0; reg < 4; ++reg) {
        int row = wm * 64 + mi * 16 + 4 * lg + reg;
        Y[row * 132 + col] =
            acc[mi][ni][reg] + bia + resf[(size_t)(m0 + row) * 128 + col];
      }
    }
  __syncthreads();
  const int rr = tid >> 1, qq = tid & 1;
  float sum = 0.f, sum2 = 0.f;
  float4 yv[16];
#pragma unroll
  for (int c = 0; c < 16; ++c) {
    float4 y = *(const float4*)&Y[rr * 132 + qq * 64 + c * 4];
    yv[c] = y;
    sum += y.x + y.y + y.z + y.w;
    sum2 += y.x * y.x + y.y * y.y + y.z * y.z + y.w * y.w;
  }
  sum += __shfl_xor(sum, 1);
  sum2 += __shfl_xor(sum2, 1);
  const float mean = sum * (1.f / 128.f);
  const float var = sum2 * (1.f / 128.f) - mean * mean;
  const float rstd = rsqrtf(var + 1e-5f);
#pragma unroll
  for (int c = 0; c < 16; ++c) {
    float4 gv = ((const float4*)gam)[qq * 16 + c];
    float4 bv = ((const float4*)bet)[qq * 16 + c];
    float4 y = yv[c];
    y.x = (y.x - mean) * rstd * gv.x + bv.x;
    y.y = (y.y - mean) * rstd * gv.y + bv.y;
    y.z = (y.z - mean) * rstd * gv.z + bv.z;
    y.w = (y.w - mean) * rstd * gv.w + bv.w;
    ((float4*)outf)[(size_t)(m0 + rr) * 32 + qq * 16 + c] = y;
    *(ushort4*)&outb[(size_t)(m0 + rr) * 128 + qq * 64 + c * 4] =
        make_ushort4(f2b(y.x), f2b(y.y), f2b(y.z), f2b(y.w));
  }
}

// ---------------------------------------------------------------------------
// FFN v2 — barrier-free, zero LDS. Each wave owns 16 tokens (r = token).
// FF1 swapped: h = mfma(W1,x) -> lane holds h[n=4lg+g][tok=r] in regs.
// bias+relu+pack -> pa (k-map 4lg+(e&3)+16(e>>2), attention-verified).
// FF2: aO[dt] += mfma(pa, w2perm[dt]) with W2 pre-permuted (same map).
// LN in-register: token row spans the 16 r-lanes of one lg group ->
// shfl_xor(1,2,4,8) reduce. No __syncthreads anywhere.
// ---------------------------------------------------------------------------
__global__ __launch_bounds__(256, 2) void k_ffn2(
    const unsigned short* __restrict__ x, const unsigned short* __restrict__ w1b,
    const float* __restrict__ b1, const unsigned short* __restrict__ w2p,
    const float* __restrict__ b2, const float* __restrict__ gam,
    const float* __restrict__ bet, float* __restrict__ featf,
    unsigned short* __restrict__ featb) {
  const int tid = threadIdx.x;
  const int lane = tid & 63, w = tid >> 6;
  const int lg = lane >> 4, r = lane & 15;
  const int tokb = blockIdx.x * 64 + w * 16;

  // x for token r, full K=128 (held in regs for all 16 chunks)
  short8 xf[4];
  const unsigned short* xp = x + (size_t)(tokb + r) * 128 + lg * 8;
#pragma unroll
  for (int kc = 0; kc < 4; ++kc) xf[kc] = *(const short8*)(xp + kc * 32);

  f32x4 aO[8];
#pragma unroll
  for (int dt = 0; dt < 8; ++dt) aO[dt] = (f32x4){0.f, 0.f, 0.f, 0.f};

  const unsigned short* w1base = w1b + (size_t)r * 128 + lg * 8;
  const unsigned short* w2base = w2p + (size_t)r * 512 + lg * 8;

#pragma unroll
  for (int c = 0; c < 16; ++c) {
    f32x4 hA = (f32x4){0.f, 0.f, 0.f, 0.f};
    f32x4 hB = (f32x4){0.f, 0.f, 0.f, 0.f};
#pragma unroll
    for (int kc = 0; kc < 4; ++kc) {
      short8 wA = *(const short8*)(w1base + (size_t)(32 * c) * 128 + kc * 32);
      short8 wB = *(const short8*)(w1base + (size_t)(32 * c + 16) * 128 + kc * 32);
      hA = __builtin_amdgcn_mfma_f32_16x16x32_bf16(wA, xf[kc], hA, 0, 0, 0);
      hB = __builtin_amdgcn_mfma_f32_16x16x32_bf16(wB, xf[kc], hB, 0, 0, 0);
    }
    float pA[4], pB[4];
#pragma unroll
    for (int g = 0; g < 4; ++g) {
      pA[g] = fmaxf(hA[g] + b1[32 * c + 4 * lg + g], 0.f);
      pB[g] = fmaxf(hB[g] + b1[32 * c + 16 + 4 * lg + g], 0.f);
    }
    unsigned int d0 = ((unsigned int)f2b(pA[1]) << 16) | f2b(pA[0]);
    unsigned int d1 = ((unsigned int)f2b(pA[3]) << 16) | f2b(pA[2]);
    unsigned int d2 = ((unsigned int)f2b(pB[1]) << 16) | f2b(pB[0]);
    unsigned int d3 = ((unsigned int)f2b(pB[3]) << 16) | f2b(pB[2]);
    u32x4 pd = (u32x4){d0, d1, d2, d3};
    short8 pa = __builtin_bit_cast(short8, pd);
#pragma unroll
    for (int dt = 0; dt < 8; ++dt) {
      short8 w2f = *(const short8*)(w2base + (size_t)(dt * 16) * 512 + c * 32);
      aO[dt] = __builtin_amdgcn_mfma_f32_16x16x32_bf16(pa, w2f, aO[dt], 0, 0, 0);
    }
  }

  // Epilogue: +b2 +residual -> in-register LN -> dual store.
  float b2v[8], gv[8], bv[8];
#pragma unroll
  for (int dt = 0; dt < 8; ++dt) {
    b2v[dt] = b2[r + 16 * dt];
    gv[dt]  = gam[r + 16 * dt];
    bv[dt]  = bet[r + 16 * dt];
  }
  float yv[8][4];
  float s1[4] = {0.f, 0.f, 0.f, 0.f}, s2[4] = {0.f, 0.f, 0.f, 0.f};
#pragma unroll
  for (int g = 0; g < 4; ++g) {
    const float* fp = featf + (size_t)(tokb + 4 * lg + g) * 128 + r;
#pragma unroll
    for (int dt = 0; dt < 8; ++dt) {
      float t = aO[dt][g] + b2v[dt] + fp[16 * dt];
      yv[dt][g] = t;
      s1[g] += t;
      s2[g] += t * t;
    }
  }
#pragma unroll
  for (int g = 0; g < 4; ++g) {
#pragma unroll
    for (int d = 1; d < 16; d <<= 1) {
      s1[g] += __shfl_xor(s1[g], d);
      s2[g] += __shfl_xor(s2[g], d);
    }
    const float mean = s1[g] * (1.f / 128.f);
    const float var = s2[g] * (1.f / 128.f) - mean * mean;
    const float rstd = rsqrtf(var + 1e-5f);
    float* fo = featf + (size_t)(tokb + 4 * lg + g) * 128 + r;
    unsigned short* bo = featb + (size_t)(tokb + 4 * lg + g) * 128 + r;
#pragma unroll
    for (int dt = 0; dt < 8; ++dt) {
      float yy = (yv[dt][g] - mean) * rstd * gv[dt] + bv[dt];
      fo[16 * dt] = yy;
      bo[16 * dt] = f2b(yy);
    }
  }
}

// ---------------------------------------------------------------------------
// Final projection (DIM -> 2) + softmax.
// ---------------------------------------------------------------------------
__global__ void k_final(const float* __restrict__ feat, const float* __restrict__ pw,
                        const float* __restrict__ pb, float* __restrict__ out) {
  const int tid = threadIdx.x;
  const int tokb = blockIdx.x * 64 + (tid >> 2);
  const int qq = tid & 3;
  float d0 = 0.f, d1 = 0.f;
#pragma unroll
  for (int c = 0; c < 8; ++c) {
    float4 xv = ((const float4*)feat)[tokb * 32 + qq * 8 + c];
    float4 w0 = ((const float4*)pw)[qq * 8 + c];
    float4 w1 = ((const float4*)pw)[32 + qq * 8 + c];
    d0 += xv.x * w0.x + xv.y * w0.y + xv.z * w0.z + xv.w * w0.w;
    d1 += xv.x * w1.x + xv.y * w1.y + xv.z * w1.z + xv.w * w1.w;
  }
  d0 += __shfl_xor(d0, 1); d0 += __shfl_xor(d0, 2);
  d1 += __shfl_xor(d1, 1); d1 += __shfl_xor(d1, 2);
  if (qq == 0) {
    float l0 = d0 + pb[0], l1 = d1 + pb[1];
    float mx = fmaxf(l0, l1);
    float e0 = __expf(l0 - mx), e1 = __expf(l1 - mx);
    float inv = 1.f / (e0 + e1);
    ((float2*)out)[tokb] = make_float2(e0 * inv, e1 * inv);
  }
}

// ---------------------------------------------------------------------------
extern "C" void kernel_launch(void* const* d_in, const int* in_sizes, int n_in,
                              void* d_out, int out_size, void* d_ws, size_t ws_size,
                              hipStream_t stream) {
  const int* tok     = (const int*)d_in[0];
  const int* npad    = (const int*)d_in[1];
  const int* picked  = (const int*)d_in[2];
  const int* skipped = (const int*)d_in[3];
  const int* nupg    = (const int*)d_in[4];
  const float* emb   = (const float*)d_in[5];
  const float* inw   = (const float*)d_in[6];
  const float* inb   = (const float*)d_in[7];
  const float* outw  = (const float*)d_in[8];
  const float* outb_ = (const float*)d_in[9];
  const float* g1    = (const float*)d_in[10];
  const float* b1    = (const float*)d_in[11];
  const float* ffw1  = (const float*)d_in[12];
  const float* ffb1  = (const float*)d_in[13];
  const float* ffw2  = (const float*)d_in[14];
  const float* ffb2  = (const float*)d_in[15];
  const float* g2    = (const float*)d_in[16];
  const float* b2    = (const float*)d_in[17];
  const float* pw    = (const float*)d_in[18];
  const float* pb    = (const float*)d_in[19];

  char* wsb = (char*)d_ws;
  float*          featf = (float*)(wsb);                       // 16 MB
  unsigned short* qb    = (unsigned short*)(wsb + 16777216);   // 8 MB
  unsigned short* kbuf  = (unsigned short*)(wsb + 25165824);   // 8 MB
  unsigned short* vtb   = (unsigned short*)(wsb + 33554432);   // 8 MB
  unsigned short* featb = (unsigned short*)(wsb + 41943040);   // 8 MB
  unsigned short* obufb = (unsigned short*)(wsb + 50331648);   // 8 MB
  unsigned short* wqkvb = (unsigned short*)(wsb + 58720256);   // 384 KB
  unsigned short* woutb = (unsigned short*)(wsb + 59113472);   // 128 KB
  unsigned short* wff1b = (unsigned short*)(wsb + 59244544);   // 512 KB
  unsigned short* wff2p = (unsigned short*)(wsb + 59768832);   // 512 KB

  k_cvt_all<<<dim3(768), 256, 0, stream>>>(inw, outw, ffw1, ffw2,
                                           wqkvb, woutb, wff1b, wff2p);

  k_embed<<<dim3(CB * CS * 32 / 256), 256, 0, stream>>>(
      tok, picked, skipped, nupg, emb, featf, featb);

  for (int l = 0; l < CL; ++l) {
    k_gemm_qkv<<<dim3(256, 3), 256, 0, stream>>>(
        featb, wqkvb + (size_t)l * 49152, inb + (size_t)l * 384, qb, kbuf, vtb);
    k_attn2<<<dim3(CB * CH), 512, 0, stream>>>(
        qb, kbuf, vtb, npad, picked, skipped, obufb);
    k_gemm_ln<<<dim3(256), 256, 0, stream>>>(
        obufb, woutb + (size_t)l * 16384, outb_ + (size_t)l * 128,
        featf, featb, featf, g1 + (size_t)l * 128, b1 + (size_t)l * 128);
    k_ffn2<<<dim3(512), 256, 0, stream>>>(
        featb, wff1b + (size_t)l * 65536, ffb1 + (size_t)l * 512,
        wff2p + (size_t)l * 65536, ffb2 + (size_t)l * 128,
        g2 + (size_t)l * 128, b2 + (size_t)l * 128, featf, featb);
  }

  k_final<<<dim3(CB * CS / 64), 256, 0, stream>>>(featf, pw, pb, (float*)d_out);
}

// Round 9
// 621.489 us; speedup vs baseline: 1.1006x; 1.1006x over previous
//
#include <hip/hip_runtime.h>

// Problem constants (match reference)
#define CB   64
#define CS   512
#define CD   128
#define CH   4
#define CFF  512
#define CL   4
#define NEG_BIG -3.0e38f
#define SCALE 0.17677669529663687f   // 1/sqrt(32)
#define EXSC  0.25505654050961364f   // SCALE * log2(e)

typedef __attribute__((ext_vector_type(8))) short short8;
typedef __attribute__((ext_vector_type(4))) float f32x4;
typedef __attribute__((ext_vector_type(4))) unsigned int u32x4;

static __device__ __forceinline__ unsigned short f2b(float f) {
  union { float f; unsigned int u; } v; v.f = f;
  unsigned int u = v.u;
  unsigned int r = (u + 0x7fffu + ((u >> 16) & 1u)) >> 16;  // RNE
  return (unsigned short)r;
}

// ---------------------------------------------------------------------------
// All weights fp32 -> bf16 in one launch (block ranges: 192 | 64 | 256 | 256).
// W2 stored PERMUTED within each 32-col chunk (pos = 8*((n&15)>>2) +
// 4*((n>>4)&1) + (n&3)) to match the pa k-map (HW-verified rounds 7/8).
// ---------------------------------------------------------------------------
__global__ void k_cvt_all(const float* __restrict__ inw, const float* __restrict__ outw,
                          const float* __restrict__ ffw1, const float* __restrict__ ffw2,
                          unsigned short* __restrict__ wq, unsigned short* __restrict__ wo,
                          unsigned short* __restrict__ w1, unsigned short* __restrict__ w2) {
  int bid = blockIdx.x;
  if (bid < 512) {
    const float* src; unsigned short* dst; int base;
    if (bid < 192)      { src = inw;  dst = wq; base = bid; }
    else if (bid < 256) { src = outw; dst = wo; base = bid - 192; }
    else                { src = ffw1; dst = w1; base = bid - 256; }
    int i = base * 256 + threadIdx.x;
    float4 v = ((const float4*)src)[i];
    ((ushort4*)dst)[i] = make_ushort4(f2b(v.x), f2b(v.y), f2b(v.z), f2b(v.w));
  } else {
    int i = (bid - 512) * 256 + threadIdx.x;    // float4 group
    int flat = i * 4;
    int row = flat >> 9;                        // layer*128 + dout
    int n = flat & 511;                         // col, multiple of 4
    float4 v = ((const float4*)ffw2)[i];
    int pos = (n & 480) + 8 * ((n & 15) >> 2) + 4 * ((n >> 4) & 1);
    *(ushort4*)&w2[(size_t)row * 512 + pos] =
        make_ushort4(f2b(v.x), f2b(v.y), f2b(v.z), f2b(v.w));
  }
}

// ---------------------------------------------------------------------------
// Embedding + feature overrides; fp32 + bf16 copies of feat.
// ---------------------------------------------------------------------------
__global__ void k_embed(const int* __restrict__ tok, const int* __restrict__ picked,
                        const int* __restrict__ skipped, const int* __restrict__ nupg,
                        const float* __restrict__ emb, float* __restrict__ featf,
                        unsigned short* __restrict__ featb) {
  int idx = blockIdx.x * 256 + threadIdx.x;   // over B*S*32 float4
  int tp = idx >> 5, c4 = idx & 31;
  int t = tok[tp];
  float4 v = ((const float4*)emb)[t * 32 + c4];
  if (c4 == 0) {
    int b = tp >> 9, s = tp & 511;
    int nc = picked[b] + skipped[b];
    v.x = (s >= nc) ? 1.f : 0.f;
    v.y = (nupg[tp] > 0) ? 1.f : 0.f;
  }
  ((float4*)featf)[idx] = v;
  ((ushort4*)featb)[idx] = make_ushort4(f2b(v.x), f2b(v.y), f2b(v.z), f2b(v.w));
}

// ---------------------------------------------------------------------------
// QKV GEMM, register-direct, head-major outputs (unchanged; passing).
// ---------------------------------------------------------------------------
__global__ __launch_bounds__(256, 2) void k_gemm_qkv(
    const unsigned short* __restrict__ A, const unsigned short* __restrict__ W,
    const float* __restrict__ bias, unsigned short* __restrict__ qb,
    unsigned short* __restrict__ kb, unsigned short* __restrict__ vtb) {
  const int tid = threadIdx.x;
  const int m0 = blockIdx.x * 128;
  const int y = blockIdx.y;           // 0=Q, 1=K, 2=V
  const int n0 = y * 128;
  const int lane = tid & 63, wid = tid >> 6;
  const int wm = wid >> 1, wn = wid & 1;
  const int lg = lane >> 4, r = lane & 15;

  f32x4 acc[4][4];
#pragma unroll
  for (int mi = 0; mi < 4; ++mi)
#pragma unroll
    for (int ni = 0; ni < 4; ++ni) acc[mi][ni] = (f32x4){0.f, 0.f, 0.f, 0.f};

  const unsigned short* Ab = A + (size_t)(m0 + wm * 64 + r) * 128 + lg * 8;
  const unsigned short* Wb = W + (size_t)(n0 + wn * 64 + r) * 128 + lg * 8;
#pragma unroll
  for (int kc = 0; kc < 4; ++kc) {
    short8 af[4], wf[4];
#pragma unroll
    for (int mi = 0; mi < 4; ++mi) af[mi] = *(const short8*)(Ab + mi * 2048 + kc * 32);
#pragma unroll
    for (int ni = 0; ni < 4; ++ni) wf[ni] = *(const short8*)(Wb + ni * 2048 + kc * 32);
#pragma unroll
    for (int mi = 0; mi < 4; ++mi)
#pragma unroll
      for (int ni = 0; ni < 4; ++ni)
        acc[mi][ni] = __builtin_amdgcn_mfma_f32_16x16x32_bf16(
            af[mi], wf[ni], acc[mi][ni], 0, 0, 0);
  }

  const int bidx = m0 >> 9;  // batch (128-row tiles never straddle b)
  if (y < 2) {
    unsigned short* dst = y ? kb : qb;
    const float sc = y ? 1.f : EXSC;
#pragma unroll
    for (int mi = 0; mi < 4; ++mi)
#pragma unroll
      for (int ni = 0; ni < 4; ++ni) {
        int cl = wn * 64 + ni * 16 + r;           // col within 128-section
        int h = cl >> 5, dd = cl & 31;
        float bia = bias[n0 + cl];
        unsigned short* dp =
            dst + ((size_t)(bidx * 4 + h) * 512) * 32 + dd;
#pragma unroll
        for (int reg = 0; reg < 4; ++reg) {
          int s = (m0 + wm * 64 + mi * 16 + 4 * lg + reg) & 511;
          dp[(size_t)s * 32] = f2b((acc[mi][ni][reg] + bia) * sc);
        }
      }
  } else {
#pragma unroll
    for (int mi = 0; mi < 4; ++mi)
#pragma unroll
      for (int ni = 0; ni < 4; ++ni) {
        int cl = wn * 64 + ni * 16 + r;
        int h = cl >> 5, dd = cl & 31;
        float bia = bias[256 + cl];
        int s4 = (m0 + wm * 64 + mi * 16 + 4 * lg) & 511;  // multiple of 4
        int chunk = s4 >> 5, jl = s4 & 31;
        int p = 8 * ((jl & 15) >> 2) + 4 * (jl >> 4);      // jl&3 == 0
        ushort4 pk = make_ushort4(
            f2b(acc[mi][ni][0] + bia), f2b(acc[mi][ni][1] + bia),
            f2b(acc[mi][ni][2] + bia), f2b(acc[mi][ni][3] + bia));
        *(ushort4*)&vtb[((size_t)(bidx * 4 + h) * 32 + dd) * 512 + chunk * 32 + p] = pk;
      }
  }
}

// ---------------------------------------------------------------------------
// Flash attention v2 (unchanged; passing).
// ---------------------------------------------------------------------------
__global__ __launch_bounds__(512, 1) void k_attn2(
    const unsigned short* __restrict__ qb, const unsigned short* __restrict__ kb,
    const unsigned short* __restrict__ vtb, const int* __restrict__ npadp,
    const int* __restrict__ picked, const int* __restrict__ skipped,
    unsigned short* __restrict__ obufb) {
  __shared__ __align__(16) unsigned short Ks[CS * 40];   // 40KB
  __shared__ __align__(16) unsigned short Vt[32 * CS];   // 32KB
  const int bh = blockIdx.x, b = bh >> 2, h = bh & 3;
  const int tid = threadIdx.x;
  const unsigned short* qbp = qb + ((size_t)bh * 512) * 32;
  const unsigned short* kbp = kb + ((size_t)bh * 512) * 32;
  const unsigned short* vtp = vtb + ((size_t)bh * 32) * 512;
#pragma unroll
  for (int i = 0; i < 4; ++i) {
    int f = tid + i * 512;                       // [0, 2048)
    int row = f >> 2, c = f & 3;
    *(uint4*)&Ks[row * 40 + c * 8] = *(const uint4*)(kbp + row * 32 + c * 8);
    int rowd = f >> 6, c16 = f & 63;
    *(uint4*)((char*)Vt + rowd * 1024 + ((c16 * 16) ^ ((rowd & 7) << 4))) =
        *(const uint4*)(vtp + rowd * 512 + c16 * 8);
  }
  const int lane = tid & 63, w = tid >> 6;
  const int lg = lane >> 4, r = lane & 15;
  const int npd = npadp[b];
  const int jhi_mid = CS - (picked[b] + skipped[b]);
  short8 onesf;
#pragma unroll
  for (int e = 0; e < 8; ++e) onesf[e] = (short)0x3F80;  // bf16 1.0
  __syncthreads();

  short8 qf[4];
  int jhiR[4];
#pragma unroll
  for (int qt = 0; qt < 4; ++qt) {
    int q = w * 64 + qt * 16 + r;
    qf[qt] = *(const short8*)(qbp + (size_t)q * 32 + 8 * lg);
    jhiR[qt] = (q < jhi_mid) ? jhi_mid : CS;
  }
  f32x4 aO0[4], aO1[4], aL[4];
#pragma unroll
  for (int qt = 0; qt < 4; ++qt) {
    aO0[qt] = (f32x4){0.f, 0.f, 0.f, 0.f};
    aO1[qt] = (f32x4){0.f, 0.f, 0.f, 0.f};
    aL[qt]  = (f32x4){0.f, 0.f, 0.f, 0.f};
  }

  for (int jc = 0; jc < 16; ++jc) {
    const int j0 = jc * 32;
    short8 kf0 = *(const short8*)&Ks[(j0 + r) * 40 + 8 * lg];
    short8 kf1 = *(const short8*)&Ks[(j0 + 16 + r) * 40 + 8 * lg];
    const int jby = (j0 * 2 + 16 * lg) ^ ((r & 7) << 4);
    short8 vf0 = *(const short8*)((const char*)Vt + r * 1024 + jby);
    short8 vf1 = *(const short8*)((const char*)Vt + (16 + r) * 1024 + jby);
#pragma unroll
    for (int qt = 0; qt < 4; ++qt) {
      f32x4 z = (f32x4){0.f, 0.f, 0.f, 0.f};
      f32x4 s0 = __builtin_amdgcn_mfma_f32_16x16x32_bf16(kf0, qf[qt], z, 0, 0, 0);
      f32x4 s1 = __builtin_amdgcn_mfma_f32_16x16x32_bf16(kf1, qf[qt], z, 0, 0, 0);
      float p0[4], p1[4];
#pragma unroll
      for (int g = 0; g < 4; ++g) {
        p0[g] = exp2f(fminf(s0[g], 43.f));
        p1[g] = exp2f(fminf(s1[g], 43.f));
      }
      if (jc == 0) {
#pragma unroll
        for (int g = 0; g < 4; ++g)
          p0[g] = (4 * lg + g >= npd) ? p0[g] : 0.f;
      }
      if (jc == 15) {
#pragma unroll
        for (int g = 0; g < 4; ++g)
          p1[g] = (496 + 4 * lg + g < jhiR[qt]) ? p1[g] : 0.f;
      }
      unsigned int d0 = ((unsigned int)f2b(p0[1]) << 16) | f2b(p0[0]);
      unsigned int d1 = ((unsigned int)f2b(p0[3]) << 16) | f2b(p0[2]);
      unsigned int d2 = ((unsigned int)f2b(p1[1]) << 16) | f2b(p1[0]);
      unsigned int d3 = ((unsigned int)f2b(p1[3]) << 16) | f2b(p1[2]);
      u32x4 pd = (u32x4){d0, d1, d2, d3};
      short8 pa = __builtin_bit_cast(short8, pd);
      aL[qt]  = __builtin_amdgcn_mfma_f32_16x16x32_bf16(pa, onesf, aL[qt], 0, 0, 0);
      aO0[qt] = __builtin_amdgcn_mfma_f32_16x16x32_bf16(pa, vf0, aO0[qt], 0, 0, 0);
      aO1[qt] = __builtin_amdgcn_mfma_f32_16x16x32_bf16(pa, vf1, aO1[qt], 0, 0, 0);
    }
  }

#pragma unroll
  for (int qt = 0; qt < 4; ++qt)
#pragma unroll
    for (int g = 0; g < 4; ++g) {
      int qg = w * 64 + qt * 16 + 4 * lg + g;
      float inv = 1.f / aL[qt][g];
      unsigned short o0 = f2b(aO0[qt][g] * inv);
      unsigned short o1 = f2b(aO1[qt][g] * inv);
      if (qg < npd) {  // pad row: softmax over {qg} -> output = V[qg] exactly
        int p = 8 * (qg >> 2) + (qg & 3);  // qg < 16 -> chunk 0
        o0 = *(const unsigned short*)((const char*)Vt + r * 1024 +
                                      ((2 * p) ^ ((r & 7) << 4)));
        o1 = *(const unsigned short*)((const char*)Vt + (16 + r) * 1024 +
                                      ((2 * p) ^ ((r & 7) << 4)));
      }
      unsigned short* op = obufb + ((size_t)(b * 512 + qg)) * 128 + h * 32;
      op[r] = o0;
      op[16 + r] = o1;
    }
}

// ---------------------------------------------------------------------------
// Register-direct MFMA GEMM (K=128) + bias + residual -> LN (unchanged).
// ---------------------------------------------------------------------------
__global__ __launch_bounds__(256, 2) void k_gemm_ln(
    const unsigned short* __restrict__ A, const unsigned short* __restrict__ W,
    const float* __restrict__ bias, float* __restrict__ outf,
    unsigned short* __restrict__ outb, const float* __restrict__ resf,
    const float* __restrict__ gam, const float* __restrict__ bet) {
  const int tid = threadIdx.x;
  const int m0 = blockIdx.x * 128;
  const int lane = tid & 63, wid = tid >> 6;
  const int wm = wid >> 1, wn = wid & 1;
  const int lg = lane >> 4, r = lane & 15;

  f32x4 acc[4][4];
#pragma unroll
  for (int mi = 0; mi < 4; ++mi)
#pragma unroll
    for (int ni = 0; ni < 4; ++ni) acc[mi][ni] = (f32x4){0.f, 0.f, 0.f, 0.f};

  const unsigned short* Ab = A + (size_t)(m0 + wm * 64 + r) * 128 + lg * 8;
  const unsigned short* Wb = W + (size_t)(wn * 64 + r) * 128 + lg * 8;
#pragma unroll
  for (int kc = 0; kc < 4; ++kc) {
    short8 af[4], wf[4];
#pragma unroll
    for (int mi = 0; mi < 4; ++mi) af[mi] = *(const short8*)(Ab + mi * 2048 + kc * 32);
#pragma unroll
    for (int ni = 0; ni < 4; ++ni) wf[ni] = *(const short8*)(Wb + ni * 2048 + kc * 32);
#pragma unroll
    for (int mi = 0; mi < 4; ++mi)
#pragma unroll
      for (int ni = 0; ni < 4; ++ni)
        acc[mi][ni] = __builtin_amdgcn_mfma_f32_16x16x32_bf16(
            af[mi], wf[ni], acc[mi][ni], 0, 0, 0);
  }

  __shared__ __align__(16) float Y[128 * 132];
#pragma unroll
  for (int mi = 0; mi < 4; ++mi)
#pragma unroll
    for (int ni = 0; ni < 4; ++ni) {
      int col = wn * 64 + ni * 16 + r;
      float bia = bias[col];
#pragma unroll
      for (int reg = 0; reg < 4; ++reg) {
        int row = wm * 64 + mi * 16 + 4 * lg + reg;
        Y[row * 132 + col] =
            acc[mi][ni][reg] + bia + resf[(size_t)(m0 + row) * 128 + col];
      }
    }
  __syncthreads();
  const int rr = tid >> 1, qq = tid & 1;
  float sum = 0.f, sum2 = 0.f;
  float4 yv[16];
#pragma unroll
  for (int c = 0; c < 16; ++c) {
    float4 y = *(const float4*)&Y[rr * 132 + qq * 64 + c * 4];
    yv[c] = y;
    sum += y.x + y.y + y.z + y.w;
    sum2 += y.x * y.x + y.y * y.y + y.z * y.z + y.w * y.w;
  }
  sum += __shfl_xor(sum, 1);
  sum2 += __shfl_xor(sum2, 1);
  const float mean = sum * (1.f / 128.f);
  const float var = sum2 * (1.f / 128.f) - mean * mean;
  const float rstd = rsqrtf(var + 1e-5f);
#pragma unroll
  for (int c = 0; c < 16; ++c) {
    float4 gv = ((const float4*)gam)[qq * 16 + c];
    float4 bv = ((const float4*)bet)[qq * 16 + c];
    float4 y = yv[c];
    y.x = (y.x - mean) * rstd * gv.x + bv.x;
    y.y = (y.y - mean) * rstd * gv.y + bv.y;
    y.z = (y.z - mean) * rstd * gv.z + bv.z;
    y.w = (y.w - mean) * rstd * gv.w + bv.w;
    ((float4*)outf)[(size_t)(m0 + rr) * 32 + qq * 16 + c] = y;
    *(ushort4*)&outb[(size_t)(m0 + rr) * 128 + qq * 64 + c * 4] =
        make_ushort4(f2b(y.x), f2b(y.y), f2b(y.z), f2b(y.w));
  }
}

// ---------------------------------------------------------------------------
// FFN v3 — LDS-staged weights, double-buffered, one barrier per chunk.
// Block = 64 tokens (4 waves x 16), grid 512 (2 blocks/CU). Per 64-ff chunk:
// {issue next chunk's 8 global uint4 -> regs | 32 MFMA from swizzled LDS |
//  write regs -> other buffer | barrier}. h never leaves registers (pa-pack
// identity, HW-verified r7/r8); W2 pre-permuted (w2p) cancels the k-map.
// LDS swizzle = attention-Vt pattern ((c16*16)^((row&7)<<4)), <=2-way reads.
// ---------------------------------------------------------------------------
__global__ __launch_bounds__(256, 2) void k_ffn3(
    const unsigned short* __restrict__ x, const unsigned short* __restrict__ w1b,
    const float* __restrict__ b1, const unsigned short* __restrict__ w2p,
    const float* __restrict__ b2, const float* __restrict__ gam,
    const float* __restrict__ bet, float* __restrict__ featf,
    unsigned short* __restrict__ featb) {
  __shared__ __align__(16) char lds[65536];  // W1 buf0|buf1 (16K each), W2 buf0|buf1
  const int tid = threadIdx.x;
  const int lane = tid & 63, w = tid >> 6;
  const int lg = lane >> 4, r = lane & 15;
  const int tokb = blockIdx.x * 64 + w * 16;

  // x fragments (token r of this wave), K=128
  short8 xf[4];
  const unsigned short* xp = x + (size_t)(tokb + r) * 128 + lg * 8;
#pragma unroll
  for (int kc = 0; kc < 4; ++kc) xf[kc] = *(const short8*)(xp + kc * 32);

  f32x4 aO[8];
#pragma unroll
  for (int dt = 0; dt < 8; ++dt) aO[dt] = (f32x4){0.f, 0.f, 0.f, 0.f};

  // Staging thread roles (compile-time per t):
  //  W1: f1 = tid + t*256 -> row=f1>>4 (0..63), c16=f1&15
  //  W2: f2 = tid + t*256 -> row=f2>>3 (0..127), c8=f2&7
  const int f1row[4] = {(tid) >> 4, (tid + 256) >> 4, (tid + 512) >> 4, (tid + 768) >> 4};
  const int f1c[4]   = {tid & 15, tid & 15, tid & 15, tid & 15};
  const int f2row[4] = {(tid) >> 3, (tid + 256) >> 3, (tid + 512) >> 3, (tid + 768) >> 3};
  const int f2c[4]   = {tid & 7, tid & 7, tid & 7, tid & 7};

  uint4 pre1[4], pre2[4];
  // prologue: fetch chunk 0 and write buf0
#pragma unroll
  for (int t = 0; t < 4; ++t) {
    pre1[t] = *(const uint4*)(w1b + (size_t)f1row[t] * 128 + f1c[t] * 8);
    pre2[t] = *(const uint4*)(w2p + (size_t)f2row[t] * 512 + f2c[t] * 8);
  }
#pragma unroll
  for (int t = 0; t < 4; ++t) {
    *(uint4*)(lds + f1row[t] * 256 + ((f1c[t] * 16) ^ ((f1row[t] & 7) << 4))) = pre1[t];
    *(uint4*)(lds + 32768 + f2row[t] * 128 + ((f2c[t] * 16) ^ ((f2row[t] & 7) << 4))) = pre2[t];
  }

#pragma unroll
  for (int c = 0; c < 8; ++c) {
    if (c < 7) {  // issue next chunk's loads early (latency hides under MFMA)
#pragma unroll
      for (int t = 0; t < 4; ++t) {
        pre1[t] = *(const uint4*)(w1b + (size_t)((c + 1) * 64 + f1row[t]) * 128 + f1c[t] * 8);
        pre2[t] = *(const uint4*)(w2p + (size_t)f2row[t] * 512 + (c + 1) * 64 + f2c[t] * 8);
      }
    }
    __syncthreads();  // buf[c&1] writes visible to all waves
    const char* W1L = lds + (c & 1) * 16384;
    const char* W2L = lds + 32768 + (c & 1) * 16384;

    // FF1: h[ff-local 16nf+4lg+g][tok r] over 64 ff dims
    f32x4 hf[4];
#pragma unroll
    for (int nf = 0; nf < 4; ++nf) hf[nf] = (f32x4){0.f, 0.f, 0.f, 0.f};
#pragma unroll
    for (int kc = 0; kc < 4; ++kc) {
#pragma unroll
      for (int nf = 0; nf < 4; ++nf) {
        short8 wfr = *(const short8*)(W1L + (16 * nf + r) * 256 +
                                      ((kc * 64 + lg * 16) ^ ((r & 7) << 4)));
        hf[nf] = __builtin_amdgcn_mfma_f32_16x16x32_bf16(wfr, xf[kc], hf[nf], 0, 0, 0);
      }
    }
    // bias + relu + pack -> pa0 (ff-local 0..31), pa1 (32..63)
    const float* b1c = b1 + 64 * c;
    float pv[4][4];
#pragma unroll
    for (int nf = 0; nf < 4; ++nf)
#pragma unroll
      for (int g = 0; g < 4; ++g)
        pv[nf][g] = fmaxf(hf[nf][g] + b1c[16 * nf + 4 * lg + g], 0.f);
    unsigned int e0 = ((unsigned int)f2b(pv[0][1]) << 16) | f2b(pv[0][0]);
    unsigned int e1 = ((unsigned int)f2b(pv[0][3]) << 16) | f2b(pv[0][2]);
    unsigned int e2 = ((unsigned int)f2b(pv[1][1]) << 16) | f2b(pv[1][0]);
    unsigned int e3 = ((unsigned int)f2b(pv[1][3]) << 16) | f2b(pv[1][2]);
    unsigned int e4 = ((unsigned int)f2b(pv[2][1]) << 16) | f2b(pv[2][0]);
    unsigned int e5 = ((unsigned int)f2b(pv[2][3]) << 16) | f2b(pv[2][2]);
    unsigned int e6 = ((unsigned int)f2b(pv[3][1]) << 16) | f2b(pv[3][0]);
    unsigned int e7 = ((unsigned int)f2b(pv[3][3]) << 16) | f2b(pv[3][2]);
    u32x4 pd0 = (u32x4){e0, e1, e2, e3};
    u32x4 pd1 = (u32x4){e4, e5, e6, e7};
    short8 pa0 = __builtin_bit_cast(short8, pd0);
    short8 pa1 = __builtin_bit_cast(short8, pd1);

    // FF2: aO[dt] += pa_s x W2frag[s][dt]
#pragma unroll
    for (int dt = 0; dt < 8; ++dt) {
      short8 w2f0 = *(const short8*)(W2L + (16 * dt + r) * 128 +
                                     ((lg * 16) ^ ((r & 7) << 4)));
      short8 w2f1 = *(const short8*)(W2L + (16 * dt + r) * 128 +
                                     ((64 + lg * 16) ^ ((r & 7) << 4)));
      aO[dt] = __builtin_amdgcn_mfma_f32_16x16x32_bf16(pa0, w2f0, aO[dt], 0, 0, 0);
      aO[dt] = __builtin_amdgcn_mfma_f32_16x16x32_bf16(pa1, w2f1, aO[dt], 0, 0, 0);
    }

    if (c < 7) {  // write prefetched chunk into the other buffer
      char* W1N = lds + ((c + 1) & 1) * 16384;
      char* W2N = lds + 32768 + ((c + 1) & 1) * 16384;
#pragma unroll
      for (int t = 0; t < 4; ++t) {
        *(uint4*)(W1N + f1row[t] * 256 + ((f1c[t] * 16) ^ ((f1row[t] & 7) << 4))) = pre1[t];
        *(uint4*)(W2N + f2row[t] * 128 + ((f2c[t] * 16) ^ ((f2row[t] & 7) << 4))) = pre2[t];
      }
    }
  }

  // Epilogue: +b2 +residual -> in-register LN -> dual store (verified r8).
  float b2v[8], gv[8], bv[8];
#pragma unroll
  for (int dt = 0; dt < 8; ++dt) {
    b2v[dt] = b2[r + 16 * dt];
    gv[dt]  = gam[r + 16 * dt];
    bv[dt]  = bet[r + 16 * dt];
  }
  float yv[8][4];
  float s1[4] = {0.f, 0.f, 0.f, 0.f}, s2[4] = {0.f, 0.f, 0.f, 0.f};
#pragma unroll
  for (int g = 0; g < 4; ++g) {
    const float* fp = featf + (size_t)(tokb + 4 * lg + g) * 128 + r;
#pragma unroll
    for (int dt = 0; dt < 8; ++dt) {
      float t = aO[dt][g] + b2v[dt] + fp[16 * dt];
      yv[dt][g] = t;
      s1[g] += t;
      s2[g] += t * t;
    }
  }
#pragma unroll
  for (int g = 0; g < 4; ++g) {
#pragma unroll
    for (int d = 1; d < 16; d <<= 1) {
      s1[g] += __shfl_xor(s1[g], d);
      s2[g] += __shfl_xor(s2[g], d);
    }
    const float mean = s1[g] * (1.f / 128.f);
    const float var = s2[g] * (1.f / 128.f) - mean * mean;
    const float rstd = rsqrtf(var + 1e-5f);
    float* fo = featf + (size_t)(tokb + 4 * lg + g) * 128 + r;
    unsigned short* bo = featb + (size_t)(tokb + 4 * lg + g) * 128 + r;
#pragma unroll
    for (int dt = 0; dt < 8; ++dt) {
      float yy = (yv[dt][g] - mean) * rstd * gv[dt] + bv[dt];
      fo[16 * dt] = yy;
      bo[16 * dt] = f2b(yy);
    }
  }
}

// ---------------------------------------------------------------------------
// Final projection (DIM -> 2) + softmax.
// ---------------------------------------------------------------------------
__global__ void k_final(const float* __restrict__ feat, const float* __restrict__ pw,
                        const float* __restrict__ pb, float* __restrict__ out) {
  const int tid = threadIdx.x;
  const int tokb = blockIdx.x * 64 + (tid >> 2);
  const int qq = tid & 3;
  float d0 = 0.f, d1 = 0.f;
#pragma unroll
  for (int c = 0; c < 8; ++c) {
    float4 xv = ((const float4*)feat)[tokb * 32 + qq * 8 + c];
    float4 w0 = ((const float4*)pw)[qq * 8 + c];
    float4 w1 = ((const float4*)pw)[32 + qq * 8 + c];
    d0 += xv.x * w0.x + xv.y * w0.y + xv.z * w0.z + xv.w * w0.w;
    d1 += xv.x * w1.x + xv.y * w1.y + xv.z * w1.z + xv.w * w1.w;
  }
  d0 += __shfl_xor(d0, 1); d0 += __shfl_xor(d0, 2);
  d1 += __shfl_xor(d1, 1); d1 += __shfl_xor(d1, 2);
  if (qq == 0) {
    float l0 = d0 + pb[0], l1 = d1 + pb[1];
    float mx = fmaxf(l0, l1);
    float e0 = __expf(l0 - mx), e1 = __expf(l1 - mx);
    float inv = 1.f / (e0 + e1);
    ((float2*)out)[tokb] = make_float2(e0 * inv, e1 * inv);
  }
}

// ---------------------------------------------------------------------------
extern "C" void kernel_launch(void* const* d_in, const int* in_sizes, int n_in,
                              void* d_out, int out_size, void* d_ws, size_t ws_size,
                              hipStream_t stream) {
  const int* tok     = (const int*)d_in[0];
  const int* npad    = (const int*)d_in[1];
  const int* picked  = (const int*)d_in[2];
  const int* skipped = (const int*)d_in[3];
  const int* nupg    = (const int*)d_in[4];
  const float* emb   = (const float*)d_in[5];
  const float* inw   = (const float*)d_in[6];
  const float* inb   = (const float*)d_in[7];
  const float* outw  = (const float*)d_in[8];
  const float* outb_ = (const float*)d_in[9];
  const float* g1    = (const float*)d_in[10];
  const float* b1    = (const float*)d_in[11];
  const float* ffw1  = (const float*)d_in[12];
  const float* ffb1  = (const float*)d_in[13];
  const float* ffw2  = (const float*)d_in[14];
  const float* ffb2  = (const float*)d_in[15];
  const float* g2    = (const float*)d_in[16];
  const float* b2    = (const float*)d_in[17];
  const float* pw    = (const float*)d_in[18];
  const float* pb    = (const float*)d_in[19];

  char* wsb = (char*)d_ws;
  float*          featf = (float*)(wsb);                       // 16 MB
  unsigned short* qb    = (unsigned short*)(wsb + 16777216);   // 8 MB
  unsigned short* kbuf  = (unsigned short*)(wsb + 25165824);   // 8 MB
  unsigned short* vtb   = (unsigned short*)(wsb + 33554432);   // 8 MB
  unsigned short* featb = (unsigned short*)(wsb + 41943040);   // 8 MB
  unsigned short* obufb = (unsigned short*)(wsb + 50331648);   // 8 MB
  unsigned short* wqkvb = (unsigned short*)(wsb + 58720256);   // 384 KB
  unsigned short* woutb = (unsigned short*)(wsb + 59113472);   // 128 KB
  unsigned short* wff1b = (unsigned short*)(wsb + 59244544);   // 512 KB
  unsigned short* wff2p = (unsigned short*)(wsb + 59768832);   // 512 KB

  k_cvt_all<<<dim3(768), 256, 0, stream>>>(inw, outw, ffw1, ffw2,
                                           wqkvb, woutb, wff1b, wff2p);

  k_embed<<<dim3(CB * CS * 32 / 256), 256, 0, stream>>>(
      tok, picked, skipped, nupg, emb, featf, featb);

  for (int l = 0; l < CL; ++l) {
    k_gemm_qkv<<<dim3(256, 3), 256, 0, stream>>>(
        featb, wqkvb + (size_t)l * 49152, inb + (size_t)l * 384, qb, kbuf, vtb);
    k_attn2<<<dim3(CB * CH), 512, 0, stream>>>(
        qb, kbuf, vtb, npad, picked, skipped, obufb);
    k_gemm_ln<<<dim3(256), 256, 0, stream>>>(
        obufb, woutb + (size_t)l * 16384, outb_ + (size_t)l * 128,
        featf, featb, featf, g1 + (size_t)l * 128, b1 + (size_t)l * 128);
    k_ffn3<<<dim3(512), 256, 0, stream>>>(
        featb, wff1b + (size_t)l * 65536, ffb1 + (size_t)l * 512,
        wff2p + (size_t)l * 65536, ffb2 + (size_t)l * 128,
        g2 + (size_t)l * 128, b2 + (size_t)l * 128, featf, featb);
  }

  k_final<<<dim3(CB * CS / 64), 256, 0, stream>>>(featf, pw, pb, (float*)d_out);
}